// Round 10
// baseline (190.456 us; speedup 1.0000x reference)
//
#include <hip/hip_runtime.h>
#include <hip/hip_fp16.h>
#include <type_traits>

#define N_NODES 50000
#define IN_F    128
#define HID_F   128
#define OUT_F   64
#define E_EDGES 800000

#define RPB   128                                  // rows per bucket
#define NBUCK ((N_NODES + RPB - 1) / RPB)          // 391
#define BCAP  2560                                 // capacity (mean 2048, +11 sigma)
#define BIN_T   512
#define BIN_EPT 16
#define BIN_EPB (BIN_T * BIN_EPT)                  // 8192 edges per block
#define BIN_NB  ((E_EDGES + BIN_EPB - 1) / BIN_EPB)  // 98

// sort key = (row_local << 3) | (col >> 13): orders each row's edges by
// 8192-col ranges (2 MB of fp16 sup -> per-XCD-L2-resident) for gather locality
#define CRB   13
#define NKEY  (RPB << 3)                           // 1024 bins

typedef _Float16 half8 __attribute__((ext_vector_type(8)));
typedef float    floatx4 __attribute__((ext_vector_type(4)));

// ---------------- Prep: zero gfill + convert W0/W1 to fp16 transposed -------
__global__ __launch_bounds__(256) void prep_kernel(const float* __restrict__ W0,
                                                   const float* __restrict__ W1,
                                                   __half* __restrict__ wt0,
                                                   __half* __restrict__ wt1,
                                                   int* __restrict__ gfill) {
    int tid = blockIdx.x * 256 + threadIdx.x;
    if (tid < IN_F * HID_F) {               // wt0[n][k] = W0[k][n], 128x128
        int k = tid >> 7, n = tid & 127;
        wt0[n * IN_F + k] = __float2half(W0[tid]);
    }
    if (tid < HID_F * OUT_F) {              // wt1[n][k] = W1[k][n], 128x64
        int k = tid / OUT_F, n = tid % OUT_F;
        wt1[n * HID_F + k] = __float2half(W1[tid]);
    }
    if (tid < 2 * NBUCK) gfill[tid] = 0;
}

// ---------------- MFMA GEMM: C[M,NF] = act(A)[M,K] @ W[K,NF] ----------------
template<int K, int NF, bool RELU_A, typename AT>
__global__ __launch_bounds__(256) void gemm_mfma_kernel(const AT* __restrict__ A,
                                                        const __half* __restrict__ Wt,
                                                        __half* __restrict__ C, int M) {
    constexpr int KP = K + 8;          // +16B stride: 2-way bank alias (free)
    constexpr int NT = NF / 16;
    __shared__ _Float16 Ws[NF * KP];
    const int tid = threadIdx.x;
    constexpr int CH = NF * K / 8;
    for (int c = tid; c < CH; c += 256) {
        const int n = c / (K / 8), ko = (c % (K / 8)) * 8;
        *(half8*)&Ws[n * KP + ko] = *(const half8*)(Wt + n * K + ko);
    }
    __syncthreads();

    const int wv = tid >> 6, lane = tid & 63;
    const int quad = lane >> 4, l16 = lane & 15;
    const int rowb = blockIdx.x * 64 + wv * 16;
    const int arow = rowb + l16;

    floatx4 acc[NT] = {};
#pragma unroll
    for (int ks = 0; ks < K; ks += 32) {
        half8 af = {};
        if (arow < M) {
            if constexpr (std::is_same<AT, float>::value) {
                const float4* p = (const float4*)(A + (long)arow * K + ks + quad * 8);
                float4 u = p[0], w = p[1];
                af[0] = (_Float16)u.x; af[1] = (_Float16)u.y;
                af[2] = (_Float16)u.z; af[3] = (_Float16)u.w;
                af[4] = (_Float16)w.x; af[5] = (_Float16)w.y;
                af[6] = (_Float16)w.z; af[7] = (_Float16)w.w;
            } else {
                af = *(const half8*)(A + (long)arow * K + ks + quad * 8);
            }
        }
        if (RELU_A) {
            _Float16 z = (_Float16)0;
#pragma unroll
            for (int j = 0; j < 8; ++j) af[j] = af[j] > z ? af[j] : z;
        }
#pragma unroll
        for (int t = 0; t < NT; ++t) {
            half8 bf = *(const half8*)&Ws[(t * 16 + l16) * KP + ks + quad * 8];
            acc[t] = __builtin_amdgcn_mfma_f32_16x16x32_f16(af, bf, acc[t], 0, 0, 0);
        }
    }
#pragma unroll
    for (int t = 0; t < NT; ++t) {
        const int col = t * 16 + l16;
#pragma unroll
        for (int i = 0; i < 4; ++i) {
            const int row = rowb + quad * 4 + i;
            if (row < M) C[(long)row * NF + col] = __float2half(acc[t][i]);
        }
    }
}

// ---------------- Coalesced bucket binning ----------------
__global__ __launch_bounds__(BIN_T) void bin_kernel(
        const int* __restrict__ row0, const int* __restrict__ col0, const float* __restrict__ val0,
        const int* __restrict__ row1, const int* __restrict__ col1, const float* __restrict__ val1,
        int* __restrict__ gfill, int2* __restrict__ bcv0, int2* __restrict__ bcv1) {
    const int g = blockIdx.y;
    const int*   rowi = g ? row1 : row0;
    const int*   coli = g ? col1 : col0;
    const float* vali = g ? val1 : val0;
    int*  gf  = gfill + g * NBUCK;
    int2* bcv = g ? bcv1 : bcv0;

    __shared__ int lhist[NBUCK];
    __shared__ int lbase[NBUCK];
    const int tid = threadIdx.x;
    for (int i = tid; i < NBUCK; i += BIN_T) lhist[i] = 0;
    __syncthreads();

    int rnk[BIN_EPT], bkt[BIN_EPT], cl[BIN_EPT], rw[BIN_EPT];
    float vl[BIN_EPT];
    const int e0 = blockIdx.x * BIN_EPB;
#pragma unroll
    for (int i = 0; i < BIN_EPT; ++i) {
        const int e = e0 + i * BIN_T + tid;
        bkt[i] = -1;
        if (e < E_EDGES) {
            const int r = rowi[e];
            rw[i] = r; cl[i] = coli[e]; vl[i] = vali[e];
            const int b = r / RPB;
            bkt[i] = b;
            rnk[i] = atomicAdd(&lhist[b], 1);
        }
    }
    __syncthreads();
    for (int i = tid; i < NBUCK; i += BIN_T) {
        const int c = lhist[i];
        lbase[i] = c ? atomicAdd(&gf[i], c) : 0;
    }
    __syncthreads();
#pragma unroll
    for (int i = 0; i < BIN_EPT; ++i) {
        if (bkt[i] >= 0) {
            const int pos = lbase[bkt[i]] + rnk[i];
            if (pos < BCAP)
                bcv[(long)bkt[i] * BCAP + pos] =
                    make_int2(((rw[i] & (RPB - 1)) << 16) | cl[i], __float_as_int(vl[i]));
        }
    }
}

// ---------------- Per-bucket counting sort by (row_local, col-range) -------
#define SORT_T 512
#define SORT_EPT (BCAP / SORT_T)    // 5
__device__ __forceinline__ int sort_key(int packed) {
    return ((packed >> 16) << 3) | ((packed & 0xFFFF) >> CRB);
}
__global__ __launch_bounds__(SORT_T) void sort_kernel(const int* __restrict__ gfill,
                                                      int2* __restrict__ bcv0,
                                                      int2* __restrict__ bcv1,
                                                      int* __restrict__ rs0,
                                                      int* __restrict__ rs1) {
    const int g = blockIdx.y;
    const int b = blockIdx.x;
    int2* buf = (g ? bcv1 : bcv0) + (long)b * BCAP;
    int*  rs  = (g ? rs1 : rs0) + b * (RPB + 1);

    __shared__ int2 sbuf[BCAP];       // 20 KB
    __shared__ int  cur[NKEY];        // 4 KB: cursor per key
    __shared__ int  sc[NKEY];         // 4 KB: scan scratch

    const int tid = threadIdx.x;
    int cnt = gfill[g * NBUCK + b];
    if (cnt > BCAP) cnt = BCAP;

    // single coalesced read into registers
    int2 ed[SORT_EPT];
#pragma unroll
    for (int k = 0; k < SORT_EPT; ++k) {
        const int e = tid + k * SORT_T;
        if (e < cnt) ed[k] = buf[e];
    }

    cur[tid] = 0; cur[tid + SORT_T] = 0;
    __syncthreads();
#pragma unroll
    for (int k = 0; k < SORT_EPT; ++k)
        if (tid + k * SORT_T < cnt) atomicAdd(&cur[sort_key(ed[k].x)], 1);
    __syncthreads();
    sc[tid] = cur[tid]; sc[tid + SORT_T] = cur[tid + SORT_T];
    __syncthreads();
    // inclusive Hillis-Steele over 1024 bins, 2 elements/thread
    for (int off = 1; off < NKEY; off <<= 1) {
        const int i0 = tid, i1 = tid + SORT_T;
        int v0 = (i0 >= off) ? sc[i0 - off] : 0;
        int v1 = (i1 >= off) ? sc[i1 - off] : 0;
        __syncthreads();
        sc[i0] += v0; sc[i1] += v1;
        __syncthreads();
    }
    // cursors = exclusive scan; rowstarts at key = rl*8
    {
        const int i0 = tid, i1 = tid + SORT_T;
        cur[i0] = (i0 == 0) ? 0 : sc[i0 - 1];
        cur[i1] = sc[i1 - 1];
    }
    __syncthreads();
    if (tid < RPB) rs[tid] = cur[tid << 3];
    if (tid == 0) rs[RPB] = cnt;
    __syncthreads();
#pragma unroll
    for (int k = 0; k < SORT_EPT; ++k) {
        if (tid + k * SORT_T < cnt) {
            int pos = atomicAdd(&cur[sort_key(ed[k].x)], 1);
            sbuf[pos] = ed[k];
        }
    }
    __syncthreads();
#pragma unroll
    for (int k = 0; k < SORT_EPT; ++k) {
        const int e = tid + k * SORT_T;
        if (e < cnt) buf[e] = sbuf[e];
    }
}

// ---------------- SpMM: wave per row, fully pipelined padded batches -------
template<int F, int VEC, bool OUT_HALF>
__global__ __launch_bounds__(256) void spmm_kernel(const int* __restrict__ rs,
                                                   const int2* __restrict__ bcv,
                                                   const __half* __restrict__ sup,
                                                   const float* __restrict__ bias,
                                                   void* __restrict__ outv, int n) {
    static_assert(F == 64 * VEC, "one wave per row");
    const int wave = threadIdx.x >> 6;
    const int lane = threadIdx.x & 63;
    const int r = blockIdx.x * 4 + wave;
    if (r >= n) return;
    const int b  = r >> 7;
    const int rl = r & (RPB - 1);
    const int* rsb = rs + b * (RPB + 1);
    const int start = rsb[rl];
    const int end   = rsb[rl + 1];
    const int2* eb = bcv + (long)b * BCAP;
    const int f0 = lane * VEC;
    float acc0 = bias[f0];
    float acc1 = (VEC == 2) ? bias[f0 + 1] : 0.f;

    for (int base = start; base < end; base += 64) {
        const int m = min(64, end - base);
        int2 cvl = make_int2(0, 0);
        if (lane < m) cvl = eb[base + lane];
        for (int j = 0; j < m; j += 8) {
            int   p[8];
            float v[8];
#pragma unroll
            for (int q = 0; q < 8; ++q) {
                p[q] = __shfl(cvl.x, j + q, 64);      // lanes >= m give (0,0)
                v[q] = __int_as_float(__shfl(cvl.y, j + q, 64));
            }
            if constexpr (VEC == 2) {
                __half2 s[8];
#pragma unroll
                for (int q = 0; q < 8; ++q)
                    s[q] = *(const __half2*)(sup + (long)(p[q] & 0xFFFF) * F + f0);
#pragma unroll
                for (int q = 0; q < 8; ++q) {
                    float2 gq = __half22float2(s[q]);
                    acc0 += v[q] * gq.x; acc1 += v[q] * gq.y;
                }
            } else {
                float s[8];
#pragma unroll
                for (int q = 0; q < 8; ++q)
                    s[q] = __half2float(sup[(long)(p[q] & 0xFFFF) * F + f0]);
#pragma unroll
                for (int q = 0; q < 8; ++q) acc0 += v[q] * s[q];
            }
        }
    }
    if constexpr (OUT_HALF) {
        __half* out = (__half*)outv;
        *(__half2*)(out + (long)r * F + f0) = __floats2half2_rn(acc0, acc1);
    } else {
        float* out = (float*)outv;
        out[(long)r * F + f0] = acc0;
    }
}

extern "C" void kernel_launch(void* const* d_in, const int* in_sizes, int n_in,
                              void* d_out, int out_size, void* d_ws, size_t ws_size,
                              hipStream_t stream) {
    const float* x    = (const float*)d_in[0];
    const int*   row0 = (const int*)d_in[1];
    const int*   col0 = (const int*)d_in[2];
    const float* val0 = (const float*)d_in[3];
    const int*   row1 = (const int*)d_in[4];
    const int*   col1 = (const int*)d_in[5];
    const float* val1 = (const float*)d_in[6];
    const float* W0   = (const float*)d_in[7];
    const float* b0   = (const float*)d_in[8];
    const float* W1   = (const float*)d_in[9];
    const float* b1   = (const float*)d_in[10];
    float* out = (float*)d_out;

    const int M = N_NODES;

    __half* sup0 = (__half*)d_ws;
    __half* h    = sup0 + (long)N_NODES * HID_F;
    int2* bcv0   = (int2*)(h + (long)N_NODES * HID_F);
    int2* bcv1   = bcv0 + (long)NBUCK * BCAP;
    int*  rs0    = (int*)(bcv1 + (long)NBUCK * BCAP);
    int*  rs1    = rs0 + NBUCK * (RPB + 1);
    int*  gfill  = rs1 + NBUCK * (RPB + 1);
    __half* wt0  = (__half*)(gfill + 2 * NBUCK + 2);  // [HID_F][IN_F]
    __half* wt1  = wt0 + IN_F * HID_F;                 // [OUT_F][HID_F]
    __half* sup1 = sup0;

    const int SPMM_B = (N_NODES + 3) / 4;

    // ---- Prep (zero gfill + W converts) + sorted-bucket build ----
    prep_kernel<<<(IN_F * HID_F + 255) / 256, 256, 0, stream>>>(W0, W1, wt0, wt1, gfill);
    bin_kernel<<<dim3(BIN_NB, 2), BIN_T, 0, stream>>>(row0, col0, val0, row1, col1, val1,
                                                      gfill, bcv0, bcv1);
    sort_kernel<<<dim3(NBUCK, 2), SORT_T, 0, stream>>>(gfill, bcv0, bcv1, rs0, rs1);

    // ---- Layer 0 ----
    gemm_mfma_kernel<IN_F, HID_F, false, float><<<(M + 63) / 64, 256, 0, stream>>>(x, wt0, sup0, M);
    spmm_kernel<HID_F, 2, true><<<SPMM_B, 256, 0, stream>>>(rs0, bcv0, sup0, b0, h, N_NODES);

    // ---- Layer 1 ----
    gemm_mfma_kernel<HID_F, OUT_F, true, __half><<<(M + 63) / 64, 256, 0, stream>>>(h, wt1, sup1, M);
    spmm_kernel<OUT_F, 1, false><<<SPMM_B, 256, 0, stream>>>(rs1, bcv1, sup1, b1, out, N_NODES);
}

// Round 11
// 184.865 us; speedup vs baseline: 1.0302x; 1.0302x over previous
//
#include <hip/hip_runtime.h>
#include <hip/hip_fp16.h>
#include <type_traits>

#define N_NODES 50000
#define IN_F    128
#define HID_F   128
#define OUT_F   64
#define E_EDGES 800000

#define RPB   128                                  // rows per bucket
#define NBUCK ((N_NODES + RPB - 1) / RPB)          // 391
#define BCAP  2560                                 // capacity (mean 2048, +11 sigma)
#define BIN_T   512
#define BIN_EPT 16
#define BIN_EPB (BIN_T * BIN_EPT)                  // 8192 edges per block
#define BIN_NB  ((E_EDGES + BIN_EPB - 1) / BIN_EPB)  // 98

typedef _Float16 half8 __attribute__((ext_vector_type(8)));
typedef float    floatx4 __attribute__((ext_vector_type(4)));

// ---------------- Prep: zero gfill + convert W0/W1 to fp16 transposed -------
__global__ __launch_bounds__(256) void prep_kernel(const float* __restrict__ W0,
                                                   const float* __restrict__ W1,
                                                   __half* __restrict__ wt0,
                                                   __half* __restrict__ wt1,
                                                   int* __restrict__ gfill) {
    int tid = blockIdx.x * 256 + threadIdx.x;
    if (tid < IN_F * HID_F) {               // wt0[n][k] = W0[k][n], 128x128
        int k = tid >> 7, n = tid & 127;
        wt0[n * IN_F + k] = __float2half(W0[tid]);
    }
    if (tid < HID_F * OUT_F) {              // wt1[n][k] = W1[k][n], 128x64
        int k = tid / OUT_F, n = tid % OUT_F;
        wt1[n * HID_F + k] = __float2half(W1[tid]);
    }
    if (tid < 2 * NBUCK) gfill[tid] = 0;
}

// ---------------- MFMA GEMM: C[M,NF] = act(A)[M,K] @ W[K,NF] ----------------
template<int K, int NF, bool RELU_A, typename AT>
__global__ __launch_bounds__(256) void gemm_mfma_kernel(const AT* __restrict__ A,
                                                        const __half* __restrict__ Wt,
                                                        __half* __restrict__ C, int M) {
    constexpr int KP = K + 8;          // +16B stride: 2-way bank alias (free)
    constexpr int NT = NF / 16;
    __shared__ _Float16 Ws[NF * KP];
    const int tid = threadIdx.x;
    constexpr int CH = NF * K / 8;
    for (int c = tid; c < CH; c += 256) {
        const int n = c / (K / 8), ko = (c % (K / 8)) * 8;
        *(half8*)&Ws[n * KP + ko] = *(const half8*)(Wt + n * K + ko);
    }
    __syncthreads();

    const int wv = tid >> 6, lane = tid & 63;
    const int quad = lane >> 4, l16 = lane & 15;
    const int rowb = blockIdx.x * 64 + wv * 16;
    const int arow = rowb + l16;

    floatx4 acc[NT] = {};
#pragma unroll
    for (int ks = 0; ks < K; ks += 32) {
        half8 af = {};
        if (arow < M) {
            if constexpr (std::is_same<AT, float>::value) {
                const float4* p = (const float4*)(A + (long)arow * K + ks + quad * 8);
                float4 u = p[0], w = p[1];
                af[0] = (_Float16)u.x; af[1] = (_Float16)u.y;
                af[2] = (_Float16)u.z; af[3] = (_Float16)u.w;
                af[4] = (_Float16)w.x; af[5] = (_Float16)w.y;
                af[6] = (_Float16)w.z; af[7] = (_Float16)w.w;
            } else {
                af = *(const half8*)(A + (long)arow * K + ks + quad * 8);
            }
        }
        if (RELU_A) {
            _Float16 z = (_Float16)0;
#pragma unroll
            for (int j = 0; j < 8; ++j) af[j] = af[j] > z ? af[j] : z;
        }
#pragma unroll
        for (int t = 0; t < NT; ++t) {
            half8 bf = *(const half8*)&Ws[(t * 16 + l16) * KP + ks + quad * 8];
            acc[t] = __builtin_amdgcn_mfma_f32_16x16x32_f16(af, bf, acc[t], 0, 0, 0);
        }
    }
#pragma unroll
    for (int t = 0; t < NT; ++t) {
        const int col = t * 16 + l16;
#pragma unroll
        for (int i = 0; i < 4; ++i) {
            const int row = rowb + quad * 4 + i;
            if (row < M) C[(long)row * NF + col] = __float2half(acc[t][i]);
        }
    }
}

// ---------------- Coalesced bucket binning ----------------
__global__ __launch_bounds__(BIN_T) void bin_kernel(
        const int* __restrict__ row0, const int* __restrict__ col0, const float* __restrict__ val0,
        const int* __restrict__ row1, const int* __restrict__ col1, const float* __restrict__ val1,
        int* __restrict__ gfill, int2* __restrict__ bcv0, int2* __restrict__ bcv1) {
    const int g = blockIdx.y;
    const int*   rowi = g ? row1 : row0;
    const int*   coli = g ? col1 : col0;
    const float* vali = g ? val1 : val0;
    int*  gf  = gfill + g * NBUCK;
    int2* bcv = g ? bcv1 : bcv0;

    __shared__ int lhist[NBUCK];
    __shared__ int lbase[NBUCK];
    const int tid = threadIdx.x;
    for (int i = tid; i < NBUCK; i += BIN_T) lhist[i] = 0;
    __syncthreads();

    int rnk[BIN_EPT], bkt[BIN_EPT], cl[BIN_EPT], rw[BIN_EPT];
    float vl[BIN_EPT];
    const int e0 = blockIdx.x * BIN_EPB;
#pragma unroll
    for (int i = 0; i < BIN_EPT; ++i) {
        const int e = e0 + i * BIN_T + tid;
        bkt[i] = -1;
        if (e < E_EDGES) {
            const int r = rowi[e];
            rw[i] = r; cl[i] = coli[e]; vl[i] = vali[e];
            const int b = r / RPB;
            bkt[i] = b;
            rnk[i] = atomicAdd(&lhist[b], 1);
        }
    }
    __syncthreads();
    for (int i = tid; i < NBUCK; i += BIN_T) {
        const int c = lhist[i];
        lbase[i] = c ? atomicAdd(&gf[i], c) : 0;
    }
    __syncthreads();
#pragma unroll
    for (int i = 0; i < BIN_EPT; ++i) {
        if (bkt[i] >= 0) {
            const int pos = lbase[bkt[i]] + rnk[i];
            if (pos < BCAP)
                bcv[(long)bkt[i] * BCAP + pos] =
                    make_int2(((rw[i] & (RPB - 1)) << 16) | cl[i], __float_as_int(vl[i]));
        }
    }
}

// ---------------- Per-bucket counting sort (single global read) ------------
#define SORT_T 512
#define SORT_EPT (BCAP / SORT_T)    // 5
__global__ __launch_bounds__(SORT_T) void sort_kernel(const int* __restrict__ gfill,
                                                      int2* __restrict__ bcv0,
                                                      int2* __restrict__ bcv1,
                                                      int* __restrict__ rs0,
                                                      int* __restrict__ rs1) {
    const int g = blockIdx.y;
    const int b = blockIdx.x;
    int2* buf = (g ? bcv1 : bcv0) + (long)b * BCAP;
    int*  rs  = (g ? rs1 : rs0) + b * (RPB + 1);

    __shared__ int2 sbuf[BCAP];       // 20 KB
    __shared__ int  cur[RPB];
    __shared__ int  sc[RPB];
    __shared__ int  start[RPB + 1];

    const int tid = threadIdx.x;
    int cnt = gfill[g * NBUCK + b];
    if (cnt > BCAP) cnt = BCAP;

    // single coalesced read into registers
    int2 ed[SORT_EPT];
#pragma unroll
    for (int k = 0; k < SORT_EPT; ++k) {
        const int e = tid + k * SORT_T;
        if (e < cnt) ed[k] = buf[e];
    }

    if (tid < RPB) cur[tid] = 0;
    __syncthreads();
#pragma unroll
    for (int k = 0; k < SORT_EPT; ++k)
        if (tid + k * SORT_T < cnt) atomicAdd(&cur[ed[k].x >> 16], 1);
    __syncthreads();
    if (tid < RPB) sc[tid] = cur[tid];
    __syncthreads();
    for (int off = 1; off < RPB; off <<= 1) {
        int v = 0;
        if (tid < RPB && tid >= off) v = sc[tid - off];
        __syncthreads();
        if (tid < RPB) sc[tid] += v;
        __syncthreads();
    }
    if (tid < RPB) {
        start[tid + 1] = sc[tid];
        if (tid == 0) start[0] = 0;
        cur[tid] = (tid == 0) ? 0 : sc[tid - 1];
    }
    __syncthreads();
#pragma unroll
    for (int k = 0; k < SORT_EPT; ++k) {
        if (tid + k * SORT_T < cnt) {
            int pos = atomicAdd(&cur[ed[k].x >> 16], 1);
            sbuf[pos] = ed[k];
        }
    }
    __syncthreads();
#pragma unroll
    for (int k = 0; k < SORT_EPT; ++k) {
        const int e = tid + k * SORT_T;
        if (e < cnt) buf[e] = sbuf[e];
    }
    for (int i = tid; i <= RPB; i += SORT_T) rs[i] = start[i];
}

// ---------------- SpMM layer 0: wave per row, padded 8-deep batches --------
// F = 128, fp16 in/out, fp32 acc. 256 B per wave-gather (full line use).
__global__ __launch_bounds__(256) void spmm_l0_kernel(const int* __restrict__ rs,
                                                      const int2* __restrict__ bcv,
                                                      const __half* __restrict__ sup,
                                                      const float* __restrict__ bias,
                                                      __half* __restrict__ out, int n) {
    const int wave = threadIdx.x >> 6;
    const int lane = threadIdx.x & 63;
    const int r = blockIdx.x * 4 + wave;
    if (r >= n) return;
    const int b  = r >> 7;
    const int rl = r & (RPB - 1);
    const int* rsb = rs + b * (RPB + 1);
    const int start = rsb[rl];
    const int end   = rsb[rl + 1];
    const int2* eb = bcv + (long)b * BCAP;
    const int f0 = lane * 2;
    float acc0 = bias[f0];
    float acc1 = bias[f0 + 1];

    for (int base = start; base < end; base += 64) {
        const int m = min(64, end - base);
        int2 cvl = make_int2(0, 0);
        if (lane < m) cvl = eb[base + lane];
        for (int j = 0; j < m; j += 8) {
            int   p[8];
            float v[8];
#pragma unroll
            for (int q = 0; q < 8; ++q) {
                p[q] = __shfl(cvl.x, j + q, 64);      // lanes >= m give (0,0)
                v[q] = __int_as_float(__shfl(cvl.y, j + q, 64));
            }
            __half2 s[8];
#pragma unroll
            for (int q = 0; q < 8; ++q)
                s[q] = *(const __half2*)(sup + (long)(p[q] & 0xFFFF) * HID_F + f0);
#pragma unroll
            for (int q = 0; q < 8; ++q) {
                float2 gq = __half22float2(s[q]);
                acc0 += v[q] * gq.x; acc1 += v[q] * gq.y;
            }
        }
    }
    *(__half2*)(out + (long)r * HID_F + f0) = __floats2half2_rn(acc0, acc1);
}

// ---------------- SpMM layer 1: half-wave per edge ----------
// F = 64 fp16 in, fp32 out. Lanes 0-31 take even batch edges, 32-63 odd;
// each lane shuffles its own edge record and gathers a half2 -> 256 B per
// wave-gather covering 2 edges; 8-deep MLP covers 16 edges per step.
// Final __shfl_xor(32) merges halves; bias added on eh==0 half only.
__global__ __launch_bounds__(256) void spmm_l1_kernel(const int* __restrict__ rs,
                                                      const int2* __restrict__ bcv,
                                                      const __half* __restrict__ sup,
                                                      const float* __restrict__ bias,
                                                      float* __restrict__ out, int n) {
    const int wave = threadIdx.x >> 6;
    const int lane = threadIdx.x & 63;
    const int r = blockIdx.x * 4 + wave;
    if (r >= n) return;
    const int b  = r >> 7;
    const int rl = r & (RPB - 1);
    const int* rsb = rs + b * (RPB + 1);
    const int start = rsb[rl];
    const int end   = rsb[rl + 1];
    const int2* eb = bcv + (long)b * BCAP;
    const int eh = lane >> 5;           // which edge of each pair
    const int li = lane & 31;
    const int f0 = li * 2;
    float acc0 = eh ? 0.f : bias[f0];
    float acc1 = eh ? 0.f : bias[f0 + 1];

    for (int base = start; base < end; base += 64) {
        const int m = min(64, end - base);
        int2 cvl = make_int2(0, 0);
        if (lane < m) cvl = eb[base + lane];
        for (int j = 0; j < m; j += 16) {
            int   p[8];
            float v[8];
#pragma unroll
            for (int q = 0; q < 8; ++q) {
                const int src = j + 2 * q + eh;       // <64; >=m lanes hold (0,0)
                p[q] = __shfl(cvl.x, src, 64);
                v[q] = __int_as_float(__shfl(cvl.y, src, 64));
            }
            __half2 s[8];
#pragma unroll
            for (int q = 0; q < 8; ++q)
                s[q] = *(const __half2*)(sup + (long)(p[q] & 0xFFFF) * OUT_F + f0);
#pragma unroll
            for (int q = 0; q < 8; ++q) {
                float2 gq = __half22float2(s[q]);
                acc0 += v[q] * gq.x; acc1 += v[q] * gq.y;
            }
        }
    }
    acc0 += __shfl_xor(acc0, 32, 64);
    acc1 += __shfl_xor(acc1, 32, 64);
    if (eh == 0)
        *(float2*)(out + (long)r * OUT_F + f0) = make_float2(acc0, acc1);
}

extern "C" void kernel_launch(void* const* d_in, const int* in_sizes, int n_in,
                              void* d_out, int out_size, void* d_ws, size_t ws_size,
                              hipStream_t stream) {
    const float* x    = (const float*)d_in[0];
    const int*   row0 = (const int*)d_in[1];
    const int*   col0 = (const int*)d_in[2];
    const float* val0 = (const float*)d_in[3];
    const int*   row1 = (const int*)d_in[4];
    const int*   col1 = (const int*)d_in[5];
    const float* val1 = (const float*)d_in[6];
    const float* W0   = (const float*)d_in[7];
    const float* b0   = (const float*)d_in[8];
    const float* W1   = (const float*)d_in[9];
    const float* b1   = (const float*)d_in[10];
    float* out = (float*)d_out;

    const int M = N_NODES;

    __half* sup0 = (__half*)d_ws;
    __half* h    = sup0 + (long)N_NODES * HID_F;
    int2* bcv0   = (int2*)(h + (long)N_NODES * HID_F);
    int2* bcv1   = bcv0 + (long)NBUCK * BCAP;
    int*  rs0    = (int*)(bcv1 + (long)NBUCK * BCAP);
    int*  rs1    = rs0 + NBUCK * (RPB + 1);
    int*  gfill  = rs1 + NBUCK * (RPB + 1);
    __half* wt0  = (__half*)(gfill + 2 * NBUCK + 2);  // [HID_F][IN_F]
    __half* wt1  = wt0 + IN_F * HID_F;                 // [OUT_F][HID_F]
    __half* sup1 = sup0;

    const int SPMM_B = (N_NODES + 3) / 4;

    // ---- Prep (zero gfill + W converts) + sorted-bucket build ----
    prep_kernel<<<(IN_F * HID_F + 255) / 256, 256, 0, stream>>>(W0, W1, wt0, wt1, gfill);
    bin_kernel<<<dim3(BIN_NB, 2), BIN_T, 0, stream>>>(row0, col0, val0, row1, col1, val1,
                                                      gfill, bcv0, bcv1);
    sort_kernel<<<dim3(NBUCK, 2), SORT_T, 0, stream>>>(gfill, bcv0, bcv1, rs0, rs1);

    // ---- Layer 0 ----
    gemm_mfma_kernel<IN_F, HID_F, false, float><<<(M + 63) / 64, 256, 0, stream>>>(x, wt0, sup0, M);
    spmm_l0_kernel<<<SPMM_B, 256, 0, stream>>>(rs0, bcv0, sup0, b0, h, N_NODES);

    // ---- Layer 1 ----
    gemm_mfma_kernel<HID_F, OUT_F, true, __half><<<(M + 63) / 64, 256, 0, stream>>>(h, wt1, sup1, M);
    spmm_l1_kernel<<<SPMM_B, 256, 0, stream>>>(rs1, bcv1, sup1, b1, out, N_NODES);
}

// Round 12
// 182.515 us; speedup vs baseline: 1.0435x; 1.0129x over previous
//
#include <hip/hip_runtime.h>
#include <hip/hip_fp16.h>
#include <type_traits>

#define N_NODES 50000
#define IN_F    128
#define HID_F   128
#define OUT_F   64
#define E_EDGES 800000

#define RPB   128                                  // rows per bucket
#define NBUCK ((N_NODES + RPB - 1) / RPB)          // 391
#define BCAP  2560                                 // capacity (mean 2048, +11 sigma)
#define BIN_T   512
#define BIN_EPT 16
#define BIN_EPB (BIN_T * BIN_EPT)                  // 8192 edges per block
#define BIN_NB  ((E_EDGES + BIN_EPB - 1) / BIN_EPB)  // 98

typedef _Float16 half8 __attribute__((ext_vector_type(8)));
typedef float    floatx4 __attribute__((ext_vector_type(4)));

// ---------------- Prep: zero gfill + convert W0/W1 to fp16 transposed -------
__global__ __launch_bounds__(256) void prep_kernel(const float* __restrict__ W0,
                                                   const float* __restrict__ W1,
                                                   __half* __restrict__ wt0,
                                                   __half* __restrict__ wt1,
                                                   int* __restrict__ gfill) {
    int tid = blockIdx.x * 256 + threadIdx.x;
    if (tid < IN_F * HID_F) {               // wt0[n][k] = W0[k][n], 128x128
        int k = tid >> 7, n = tid & 127;
        wt0[n * IN_F + k] = __float2half(W0[tid]);
    }
    if (tid < HID_F * OUT_F) {              // wt1[n][k] = W1[k][n], 128x64
        int k = tid / OUT_F, n = tid % OUT_F;
        wt1[n * HID_F + k] = __float2half(W1[tid]);
    }
    if (tid < 2 * NBUCK) gfill[tid] = 0;
}

// ---------------- MFMA GEMM (layer 1): C = relu(A) @ W, 256 threads --------
template<int K, int NF, bool RELU_A, typename AT>
__global__ __launch_bounds__(256) void gemm_mfma_kernel(const AT* __restrict__ A,
                                                        const __half* __restrict__ Wt,
                                                        __half* __restrict__ C, int M) {
    constexpr int KP = K + 8;          // +16B stride: 2-way bank alias (free)
    constexpr int NT = NF / 16;
    __shared__ _Float16 Ws[NF * KP];
    const int tid = threadIdx.x;
    constexpr int CH = NF * K / 8;
    for (int c = tid; c < CH; c += 256) {
        const int n = c / (K / 8), ko = (c % (K / 8)) * 8;
        *(half8*)&Ws[n * KP + ko] = *(const half8*)(Wt + n * K + ko);
    }
    __syncthreads();

    const int wv = tid >> 6, lane = tid & 63;
    const int quad = lane >> 4, l16 = lane & 15;
    const int rowb = blockIdx.x * 64 + wv * 16;
    const int arow = rowb + l16;

    floatx4 acc[NT] = {};
#pragma unroll
    for (int ks = 0; ks < K; ks += 32) {
        half8 af = {};
        if (arow < M) {
            if constexpr (std::is_same<AT, float>::value) {
                const float4* p = (const float4*)(A + (long)arow * K + ks + quad * 8);
                float4 u = p[0], w = p[1];
                af[0] = (_Float16)u.x; af[1] = (_Float16)u.y;
                af[2] = (_Float16)u.z; af[3] = (_Float16)u.w;
                af[4] = (_Float16)w.x; af[5] = (_Float16)w.y;
                af[6] = (_Float16)w.z; af[7] = (_Float16)w.w;
            } else {
                af = *(const half8*)(A + (long)arow * K + ks + quad * 8);
            }
        }
        if (RELU_A) {
            _Float16 z = (_Float16)0;
#pragma unroll
            for (int j = 0; j < 8; ++j) af[j] = af[j] > z ? af[j] : z;
        }
#pragma unroll
        for (int t = 0; t < NT; ++t) {
            half8 bf = *(const half8*)&Ws[(t * 16 + l16) * KP + ks + quad * 8];
            acc[t] = __builtin_amdgcn_mfma_f32_16x16x32_f16(af, bf, acc[t], 0, 0, 0);
        }
    }
#pragma unroll
    for (int t = 0; t < NT; ++t) {
        const int col = t * 16 + l16;
#pragma unroll
        for (int i = 0; i < 4; ++i) {
            const int row = rowb + quad * 4 + i;
            if (row < M) C[(long)row * NF + col] = __float2half(acc[t][i]);
        }
    }
}

// ---------------- Coalesced bucket binning ----------------
__global__ __launch_bounds__(BIN_T) void bin_kernel(
        const int* __restrict__ row0, const int* __restrict__ col0, const float* __restrict__ val0,
        const int* __restrict__ row1, const int* __restrict__ col1, const float* __restrict__ val1,
        int* __restrict__ gfill, int2* __restrict__ bcv0, int2* __restrict__ bcv1) {
    const int g = blockIdx.y;
    const int*   rowi = g ? row1 : row0;
    const int*   coli = g ? col1 : col0;
    const float* vali = g ? val1 : val0;
    int*  gf  = gfill + g * NBUCK;
    int2* bcv = g ? bcv1 : bcv0;

    __shared__ int lhist[NBUCK];
    __shared__ int lbase[NBUCK];
    const int tid = threadIdx.x;
    for (int i = tid; i < NBUCK; i += BIN_T) lhist[i] = 0;
    __syncthreads();

    int rnk[BIN_EPT], bkt[BIN_EPT], cl[BIN_EPT], rw[BIN_EPT];
    float vl[BIN_EPT];
    const int e0 = blockIdx.x * BIN_EPB;
#pragma unroll
    for (int i = 0; i < BIN_EPT; ++i) {
        const int e = e0 + i * BIN_T + tid;
        bkt[i] = -1;
        if (e < E_EDGES) {
            const int r = rowi[e];
            rw[i] = r; cl[i] = coli[e]; vl[i] = vali[e];
            const int b = r / RPB;
            bkt[i] = b;
            rnk[i] = atomicAdd(&lhist[b], 1);
        }
    }
    __syncthreads();
    for (int i = tid; i < NBUCK; i += BIN_T) {
        const int c = lhist[i];
        lbase[i] = c ? atomicAdd(&gf[i], c) : 0;
    }
    __syncthreads();
#pragma unroll
    for (int i = 0; i < BIN_EPT; ++i) {
        if (bkt[i] >= 0) {
            const int pos = lbase[bkt[i]] + rnk[i];
            if (pos < BCAP)
                bcv[(long)bkt[i] * BCAP + pos] =
                    make_int2(((rw[i] & (RPB - 1)) << 16) | cl[i], __float_as_int(vl[i]));
        }
    }
}

// ---------------- Mid: sort (y=0,1) + layer-0 GEMM (y=2) in one dispatch ----
// Independent stages co-run on different pipes (sort: LDS atomics + global RW;
// gemm: MFMA + global read) instead of serializing as two launches.
#define MID_T 512
#define SORT_EPT (BCAP / MID_T)    // 5
union MidLds {
    struct {
        int2 sbuf[BCAP];           // 20 KB
        int  cur[RPB];
        int  sc[RPB];
        int  start[RPB + 1];
    } s;
    _Float16 ws[HID_F * (IN_F + 8)];   // 34.8 KB (dominates)
};

__global__ __launch_bounds__(MID_T) void mid_kernel(
        const int* __restrict__ gfill, int2* __restrict__ bcv0, int2* __restrict__ bcv1,
        int* __restrict__ rs0, int* __restrict__ rs1,
        const float* __restrict__ x, const __half* __restrict__ wt0,
        __half* __restrict__ sup0, int M) {
    __shared__ MidLds lds;
    const int tid = threadIdx.x;

    if (blockIdx.y < 2) {
        // ---------------- sort part ----------------
        const int g = blockIdx.y;
        const int b = blockIdx.x;
        int2* buf = (g ? bcv1 : bcv0) + (long)b * BCAP;
        int*  rs  = (g ? rs1 : rs0) + b * (RPB + 1);

        int cnt = gfill[g * NBUCK + b];
        if (cnt > BCAP) cnt = BCAP;

        int2 ed[SORT_EPT];
#pragma unroll
        for (int k = 0; k < SORT_EPT; ++k) {
            const int e = tid + k * MID_T;
            if (e < cnt) ed[k] = buf[e];
        }

        if (tid < RPB) lds.s.cur[tid] = 0;
        __syncthreads();
#pragma unroll
        for (int k = 0; k < SORT_EPT; ++k)
            if (tid + k * MID_T < cnt) atomicAdd(&lds.s.cur[ed[k].x >> 16], 1);
        __syncthreads();
        if (tid < RPB) lds.s.sc[tid] = lds.s.cur[tid];
        __syncthreads();
        for (int off = 1; off < RPB; off <<= 1) {
            int v = 0;
            if (tid < RPB && tid >= off) v = lds.s.sc[tid - off];
            __syncthreads();
            if (tid < RPB) lds.s.sc[tid] += v;
            __syncthreads();
        }
        if (tid < RPB) {
            lds.s.start[tid + 1] = lds.s.sc[tid];
            if (tid == 0) lds.s.start[0] = 0;
            lds.s.cur[tid] = (tid == 0) ? 0 : lds.s.sc[tid - 1];
        }
        __syncthreads();
#pragma unroll
        for (int k = 0; k < SORT_EPT; ++k) {
            if (tid + k * MID_T < cnt) {
                int pos = atomicAdd(&lds.s.cur[ed[k].x >> 16], 1);
                lds.s.sbuf[pos] = ed[k];
            }
        }
        __syncthreads();
#pragma unroll
        for (int k = 0; k < SORT_EPT; ++k) {
            const int e = tid + k * MID_T;
            if (e < cnt) buf[e] = lds.s.sbuf[e];
        }
        for (int i = tid; i <= RPB; i += MID_T) rs[i] = lds.s.start[i];
    } else {
        // ---------------- layer-0 GEMM part: 128 rows per block ----------
        constexpr int KP = IN_F + 8;
        constexpr int NT = HID_F / 16;
        for (int c = tid; c < HID_F * (IN_F / 8); c += MID_T) {
            const int n = c / (IN_F / 8), ko = (c % (IN_F / 8)) * 8;
            *(half8*)&lds.ws[n * KP + ko] = *(const half8*)(wt0 + n * IN_F + ko);
        }
        __syncthreads();

        const int wv = tid >> 6, lane = tid & 63;
        const int quad = lane >> 4, l16 = lane & 15;
        const int rowb = blockIdx.x * 128 + wv * 16;
        const int arow = rowb + l16;

        floatx4 acc[NT] = {};
#pragma unroll
        for (int ks = 0; ks < IN_F; ks += 32) {
            half8 af = {};
            if (arow < M) {
                const float4* p = (const float4*)(x + (long)arow * IN_F + ks + quad * 8);
                float4 u = p[0], w = p[1];
                af[0] = (_Float16)u.x; af[1] = (_Float16)u.y;
                af[2] = (_Float16)u.z; af[3] = (_Float16)u.w;
                af[4] = (_Float16)w.x; af[5] = (_Float16)w.y;
                af[6] = (_Float16)w.z; af[7] = (_Float16)w.w;
            }
#pragma unroll
            for (int t = 0; t < NT; ++t) {
                half8 bf = *(const half8*)&lds.ws[(t * 16 + l16) * KP + ks + quad * 8];
                acc[t] = __builtin_amdgcn_mfma_f32_16x16x32_f16(af, bf, acc[t], 0, 0, 0);
            }
        }
#pragma unroll
        for (int t = 0; t < NT; ++t) {
            const int col = t * 16 + l16;
#pragma unroll
            for (int i = 0; i < 4; ++i) {
                const int row = rowb + quad * 4 + i;
                if (row < M) sup0[(long)row * HID_F + col] = __float2half(acc[t][i]);
            }
        }
    }
}

// ---------------- SpMM layer 0: wave per row, padded 8-deep batches --------
__global__ __launch_bounds__(256) void spmm_l0_kernel(const int* __restrict__ rs,
                                                      const int2* __restrict__ bcv,
                                                      const __half* __restrict__ sup,
                                                      const float* __restrict__ bias,
                                                      __half* __restrict__ out, int n) {
    const int wave = threadIdx.x >> 6;
    const int lane = threadIdx.x & 63;
    const int r = blockIdx.x * 4 + wave;
    if (r >= n) return;
    const int b  = r >> 7;
    const int rl = r & (RPB - 1);
    const int* rsb = rs + b * (RPB + 1);
    const int start = rsb[rl];
    const int end   = rsb[rl + 1];
    const int2* eb = bcv + (long)b * BCAP;
    const int f0 = lane * 2;
    float acc0 = bias[f0];
    float acc1 = bias[f0 + 1];

    for (int base = start; base < end; base += 64) {
        const int m = min(64, end - base);
        int2 cvl = make_int2(0, 0);
        if (lane < m) cvl = eb[base + lane];
        for (int j = 0; j < m; j += 8) {
            int   p[8];
            float v[8];
#pragma unroll
            for (int q = 0; q < 8; ++q) {
                p[q] = __shfl(cvl.x, j + q, 64);      // lanes >= m give (0,0)
                v[q] = __int_as_float(__shfl(cvl.y, j + q, 64));
            }
            __half2 s[8];
#pragma unroll
            for (int q = 0; q < 8; ++q)
                s[q] = *(const __half2*)(sup + (long)(p[q] & 0xFFFF) * HID_F + f0);
#pragma unroll
            for (int q = 0; q < 8; ++q) {
                float2 gq = __half22float2(s[q]);
                acc0 += v[q] * gq.x; acc1 += v[q] * gq.y;
            }
        }
    }
    *(__half2*)(out + (long)r * HID_F + f0) = __floats2half2_rn(acc0, acc1);
}

// ---------------- SpMM layer 1: half-wave per edge ----------
__global__ __launch_bounds__(256) void spmm_l1_kernel(const int* __restrict__ rs,
                                                      const int2* __restrict__ bcv,
                                                      const __half* __restrict__ sup,
                                                      const float* __restrict__ bias,
                                                      float* __restrict__ out, int n) {
    const int wave = threadIdx.x >> 6;
    const int lane = threadIdx.x & 63;
    const int r = blockIdx.x * 4 + wave;
    if (r >= n) return;
    const int b  = r >> 7;
    const int rl = r & (RPB - 1);
    const int* rsb = rs + b * (RPB + 1);
    const int start = rsb[rl];
    const int end   = rsb[rl + 1];
    const int2* eb = bcv + (long)b * BCAP;
    const int eh = lane >> 5;
    const int li = lane & 31;
    const int f0 = li * 2;
    float acc0 = eh ? 0.f : bias[f0];
    float acc1 = eh ? 0.f : bias[f0 + 1];

    for (int base = start; base < end; base += 64) {
        const int m = min(64, end - base);
        int2 cvl = make_int2(0, 0);
        if (lane < m) cvl = eb[base + lane];
        for (int j = 0; j < m; j += 16) {
            int   p[8];
            float v[8];
#pragma unroll
            for (int q = 0; q < 8; ++q) {
                const int src = j + 2 * q + eh;
                p[q] = __shfl(cvl.x, src, 64);
                v[q] = __int_as_float(__shfl(cvl.y, src, 64));
            }
            __half2 s[8];
#pragma unroll
            for (int q = 0; q < 8; ++q)
                s[q] = *(const __half2*)(sup + (long)(p[q] & 0xFFFF) * OUT_F + f0);
#pragma unroll
            for (int q = 0; q < 8; ++q) {
                float2 gq = __half22float2(s[q]);
                acc0 += v[q] * gq.x; acc1 += v[q] * gq.y;
            }
        }
    }
    acc0 += __shfl_xor(acc0, 32, 64);
    acc1 += __shfl_xor(acc1, 32, 64);
    if (eh == 0)
        *(float2*)(out + (long)r * OUT_F + f0) = make_float2(acc0, acc1);
}

extern "C" void kernel_launch(void* const* d_in, const int* in_sizes, int n_in,
                              void* d_out, int out_size, void* d_ws, size_t ws_size,
                              hipStream_t stream) {
    const float* x    = (const float*)d_in[0];
    const int*   row0 = (const int*)d_in[1];
    const int*   col0 = (const int*)d_in[2];
    const float* val0 = (const float*)d_in[3];
    const int*   row1 = (const int*)d_in[4];
    const int*   col1 = (const int*)d_in[5];
    const float* val1 = (const float*)d_in[6];
    const float* W0   = (const float*)d_in[7];
    const float* b0   = (const float*)d_in[8];
    const float* W1   = (const float*)d_in[9];
    const float* b1   = (const float*)d_in[10];
    float* out = (float*)d_out;

    const int M = N_NODES;

    __half* sup0 = (__half*)d_ws;
    __half* h    = sup0 + (long)N_NODES * HID_F;
    int2* bcv0   = (int2*)(h + (long)N_NODES * HID_F);
    int2* bcv1   = bcv0 + (long)NBUCK * BCAP;
    int*  rs0    = (int*)(bcv1 + (long)NBUCK * BCAP);
    int*  rs1    = rs0 + NBUCK * (RPB + 1);
    int*  gfill  = rs1 + NBUCK * (RPB + 1);
    __half* wt0  = (__half*)(gfill + 2 * NBUCK + 2);  // [HID_F][IN_F]
    __half* wt1  = wt0 + IN_F * HID_F;                 // [OUT_F][HID_F]
    __half* sup1 = sup0;

    const int SPMM_B = (N_NODES + 3) / 4;

    // ---- Prep + bin + (sort || gemm0) ----
    prep_kernel<<<(IN_F * HID_F + 255) / 256, 256, 0, stream>>>(W0, W1, wt0, wt1, gfill);
    bin_kernel<<<dim3(BIN_NB, 2), BIN_T, 0, stream>>>(row0, col0, val0, row1, col1, val1,
                                                      gfill, bcv0, bcv1);
    mid_kernel<<<dim3(NBUCK, 3), MID_T, 0, stream>>>(gfill, bcv0, bcv1, rs0, rs1,
                                                     x, wt0, sup0, M);

    // ---- Layer 0 aggregate ----
    spmm_l0_kernel<<<SPMM_B, 256, 0, stream>>>(rs0, bcv0, sup0, b0, h, N_NODES);

    // ---- Layer 1 ----
    gemm_mfma_kernel<HID_F, OUT_F, true, __half><<<(M + 63) / 64, 256, 0, stream>>>(h, wt1, sup1, M);
    spmm_l1_kernel<<<SPMM_B, 256, 0, stream>>>(rs1, bcv1, sup1, b1, out, N_NODES);
}

// Round 13
// 179.823 us; speedup vs baseline: 1.0591x; 1.0150x over previous
//
#include <hip/hip_runtime.h>
#include <hip/hip_fp16.h>

#define N_NODES 50000
#define IN_F    128
#define HID_F   128
#define OUT_F   64
#define E_EDGES 800000

#define RPB   128                                  // rows per bucket
#define NBUCK ((N_NODES + RPB - 1) / RPB)          // 391
#define BCAP  2560                                 // capacity (mean 2048, +11 sigma)
#define BIN_T   512
#define BIN_EPT 16
#define BIN_EPB (BIN_T * BIN_EPT)                  // 8192 edges per block
#define BIN_NB  ((E_EDGES + BIN_EPB - 1) / BIN_EPB)  // 98

typedef _Float16 half8 __attribute__((ext_vector_type(8)));
typedef float    floatx4 __attribute__((ext_vector_type(4)));

// ---------------- Prep: zero gfill + convert W0/W1 to fp16 transposed -------
__global__ __launch_bounds__(256) void prep_kernel(const float* __restrict__ W0,
                                                   const float* __restrict__ W1,
                                                   __half* __restrict__ wt0,
                                                   __half* __restrict__ wt1,
                                                   int* __restrict__ gfill) {
    int tid = blockIdx.x * 256 + threadIdx.x;
    if (tid < IN_F * HID_F) {               // wt0[n][k] = W0[k][n], 128x128
        int k = tid >> 7, n = tid & 127;
        wt0[n * IN_F + k] = __float2half(W0[tid]);
    }
    if (tid < HID_F * OUT_F) {              // wt1[n][k] = W1[k][n], 128x64
        int k = tid / OUT_F, n = tid % OUT_F;
        wt1[n * HID_F + k] = __float2half(W1[tid]);
    }
    if (tid < 2 * NBUCK) gfill[tid] = 0;
}

// ---------------- Coalesced bucket binning ----------------
__global__ __launch_bounds__(BIN_T) void bin_kernel(
        const int* __restrict__ row0, const int* __restrict__ col0, const float* __restrict__ val0,
        const int* __restrict__ row1, const int* __restrict__ col1, const float* __restrict__ val1,
        int* __restrict__ gfill, int2* __restrict__ bcv0, int2* __restrict__ bcv1) {
    const int g = blockIdx.y;
    const int*   rowi = g ? row1 : row0;
    const int*   coli = g ? col1 : col0;
    const float* vali = g ? val1 : val0;
    int*  gf  = gfill + g * NBUCK;
    int2* bcv = g ? bcv1 : bcv0;

    __shared__ int lhist[NBUCK];
    __shared__ int lbase[NBUCK];
    const int tid = threadIdx.x;
    for (int i = tid; i < NBUCK; i += BIN_T) lhist[i] = 0;
    __syncthreads();

    int rnk[BIN_EPT], bkt[BIN_EPT], cl[BIN_EPT], rw[BIN_EPT];
    float vl[BIN_EPT];
    const int e0 = blockIdx.x * BIN_EPB;
#pragma unroll
    for (int i = 0; i < BIN_EPT; ++i) {
        const int e = e0 + i * BIN_T + tid;
        bkt[i] = -1;
        if (e < E_EDGES) {
            const int r = rowi[e];
            rw[i] = r; cl[i] = coli[e]; vl[i] = vali[e];
            const int b = r / RPB;
            bkt[i] = b;
            rnk[i] = atomicAdd(&lhist[b], 1);
        }
    }
    __syncthreads();
    for (int i = tid; i < NBUCK; i += BIN_T) {
        const int c = lhist[i];
        lbase[i] = c ? atomicAdd(&gf[i], c) : 0;
    }
    __syncthreads();
#pragma unroll
    for (int i = 0; i < BIN_EPT; ++i) {
        if (bkt[i] >= 0) {
            const int pos = lbase[bkt[i]] + rnk[i];
            if (pos < BCAP)
                bcv[(long)bkt[i] * BCAP + pos] =
                    make_int2(((rw[i] & (RPB - 1)) << 16) | cl[i], __float_as_int(vl[i]));
        }
    }
}

// ---------------- Mid: sort (y=0,1) + layer-0 GEMM (y=2) in one dispatch ----
#define MID_T 512
#define SORT_EPT (BCAP / MID_T)    // 5
union MidLds {
    struct {
        int2 sbuf[BCAP];           // 20 KB
        int  cur[RPB];
        int  sc[RPB];
        int  start[RPB + 1];
    } s;
    _Float16 ws[HID_F * (IN_F + 8)];   // 34.8 KB (dominates)
};

__global__ __launch_bounds__(MID_T) void mid_kernel(
        const int* __restrict__ gfill, int2* __restrict__ bcv0, int2* __restrict__ bcv1,
        int* __restrict__ rs0, int* __restrict__ rs1,
        const float* __restrict__ x, const __half* __restrict__ wt0,
        __half* __restrict__ sup0, int M) {
    __shared__ MidLds lds;
    const int tid = threadIdx.x;

    if (blockIdx.y < 2) {
        // ---------------- sort part ----------------
        const int g = blockIdx.y;
        const int b = blockIdx.x;
        int2* buf = (g ? bcv1 : bcv0) + (long)b * BCAP;
        int*  rs  = (g ? rs1 : rs0) + b * (RPB + 1);

        int cnt = gfill[g * NBUCK + b];
        if (cnt > BCAP) cnt = BCAP;

        int2 ed[SORT_EPT];
#pragma unroll
        for (int k = 0; k < SORT_EPT; ++k) {
            const int e = tid + k * MID_T;
            if (e < cnt) ed[k] = buf[e];
        }

        if (tid < RPB) lds.s.cur[tid] = 0;
        __syncthreads();
#pragma unroll
        for (int k = 0; k < SORT_EPT; ++k)
            if (tid + k * MID_T < cnt) atomicAdd(&lds.s.cur[ed[k].x >> 16], 1);
        __syncthreads();
        if (tid < RPB) lds.s.sc[tid] = lds.s.cur[tid];
        __syncthreads();
        for (int off = 1; off < RPB; off <<= 1) {
            int v = 0;
            if (tid < RPB && tid >= off) v = lds.s.sc[tid - off];
            __syncthreads();
            if (tid < RPB) lds.s.sc[tid] += v;
            __syncthreads();
        }
        if (tid < RPB) {
            lds.s.start[tid + 1] = lds.s.sc[tid];
            if (tid == 0) lds.s.start[0] = 0;
            lds.s.cur[tid] = (tid == 0) ? 0 : lds.s.sc[tid - 1];
        }
        __syncthreads();
#pragma unroll
        for (int k = 0; k < SORT_EPT; ++k) {
            if (tid + k * MID_T < cnt) {
                int pos = atomicAdd(&lds.s.cur[ed[k].x >> 16], 1);
                lds.s.sbuf[pos] = ed[k];
            }
        }
        __syncthreads();
#pragma unroll
        for (int k = 0; k < SORT_EPT; ++k) {
            const int e = tid + k * MID_T;
            if (e < cnt) buf[e] = lds.s.sbuf[e];
        }
        for (int i = tid; i <= RPB; i += MID_T) rs[i] = lds.s.start[i];
    } else {
        // ---------------- layer-0 GEMM part: 128 rows per block ----------
        constexpr int KP = IN_F + 8;
        constexpr int NT = HID_F / 16;
        for (int c = tid; c < HID_F * (IN_F / 8); c += MID_T) {
            const int n = c / (IN_F / 8), ko = (c % (IN_F / 8)) * 8;
            *(half8*)&lds.ws[n * KP + ko] = *(const half8*)(wt0 + n * IN_F + ko);
        }
        __syncthreads();

        const int wv = tid >> 6, lane = tid & 63;
        const int quad = lane >> 4, l16 = lane & 15;
        const int rowb = blockIdx.x * 128 + wv * 16;
        const int arow = rowb + l16;

        floatx4 acc[NT] = {};
#pragma unroll
        for (int ks = 0; ks < IN_F; ks += 32) {
            half8 af = {};
            if (arow < M) {
                const float4* p = (const float4*)(x + (long)arow * IN_F + ks + quad * 8);
                float4 u = p[0], w = p[1];
                af[0] = (_Float16)u.x; af[1] = (_Float16)u.y;
                af[2] = (_Float16)u.z; af[3] = (_Float16)u.w;
                af[4] = (_Float16)w.x; af[5] = (_Float16)w.y;
                af[6] = (_Float16)w.z; af[7] = (_Float16)w.w;
            }
#pragma unroll
            for (int t = 0; t < NT; ++t) {
                half8 bf = *(const half8*)&lds.ws[(t * 16 + l16) * KP + ks + quad * 8];
                acc[t] = __builtin_amdgcn_mfma_f32_16x16x32_f16(af, bf, acc[t], 0, 0, 0);
            }
        }
#pragma unroll
        for (int t = 0; t < NT; ++t) {
            const int col = t * 16 + l16;
#pragma unroll
            for (int i = 0; i < 4; ++i) {
                const int row = rowb + quad * 4 + i;
                if (row < M) sup0[(long)row * HID_F + col] = __float2half(acc[t][i]);
            }
        }
    }
}

// ---------------- Fused layer-0 aggregate + bias/relu + layer-1 GEMM -------
// Block = 16 rows (one 128-row bucket contains them all). Phase 1: 4 waves x
// 4 rows run the padded-8-deep edge aggregation; h tile (16x128 fp16) goes to
// LDS (stride 136 halves => 2-way bank alias only). Phase 2: each wave does
// one 16x16 col-tile of relu(h)@W1 via 16x16x32 MFMA (A from LDS, B from
// L2-hot wt1), writing sup1 directly. Deletes the h global round-trip.
__global__ __launch_bounds__(256) void agg_gemm_kernel(const int* __restrict__ rs,
                                                       const int2* __restrict__ bcv,
                                                       const __half* __restrict__ sup,
                                                       const float* __restrict__ bias,
                                                       const __half* __restrict__ wt1,
                                                       __half* __restrict__ sup1) {
    constexpr int HP = HID_F + 8;     // LDS row stride in halves
    __shared__ _Float16 ht[16 * HP];
    const int wv   = threadIdx.x >> 6;
    const int lane = threadIdx.x & 63;
    const int r0 = blockIdx.x * 16;
    const int b  = r0 >> 7;
    const int* rsb = rs + b * (RPB + 1);
    const int2* eb = bcv + (long)b * BCAP;
    const int f0 = lane * 2;

    // ---- Phase 1: aggregate 4 rows per wave ----
#pragma unroll
    for (int i = 0; i < 4; ++i) {
        const int rl = (r0 & (RPB - 1)) + wv * 4 + i;
        const int start = rsb[rl];
        const int end   = rsb[rl + 1];
        float acc0 = bias[f0];
        float acc1 = bias[f0 + 1];
        for (int base = start; base < end; base += 64) {
            const int m = min(64, end - base);
            int2 cvl = make_int2(0, 0);
            if (lane < m) cvl = eb[base + lane];
            for (int j = 0; j < m; j += 8) {
                int   p[8];
                float v[8];
#pragma unroll
                for (int q = 0; q < 8; ++q) {
                    p[q] = __shfl(cvl.x, j + q, 64);      // lanes >= m give (0,0)
                    v[q] = __int_as_float(__shfl(cvl.y, j + q, 64));
                }
                __half2 s[8];
#pragma unroll
                for (int q = 0; q < 8; ++q)
                    s[q] = *(const __half2*)(sup + (long)(p[q] & 0xFFFF) * HID_F + f0);
#pragma unroll
                for (int q = 0; q < 8; ++q) {
                    float2 gq = __half22float2(s[q]);
                    acc0 += v[q] * gq.x; acc1 += v[q] * gq.y;
                }
            }
        }
        acc0 = acc0 > 0.f ? acc0 : 0.f;      // relu
        acc1 = acc1 > 0.f ? acc1 : 0.f;
        _Float16 h2[2] = { (_Float16)acc0, (_Float16)acc1 };
        *(_Float16*)&ht[(wv * 4 + i) * HP + f0]     = h2[0];
        *(_Float16*)&ht[(wv * 4 + i) * HP + f0 + 1] = h2[1];
    }
    __syncthreads();

    // ---- Phase 2: 16x64 gemm1 tile, wave wv -> cols wv*16..+15 ----
    const int quad = lane >> 4, l16 = lane & 15;
    floatx4 acc = {};
#pragma unroll
    for (int ks = 0; ks < HID_F; ks += 32) {
        half8 af = *(const half8*)&ht[l16 * HP + ks + quad * 8];
        half8 bf = *(const half8*)(wt1 + (long)(wv * 16 + l16) * HID_F + ks + quad * 8);
        acc = __builtin_amdgcn_mfma_f32_16x16x32_f16(af, bf, acc, 0, 0, 0);
    }
#pragma unroll
    for (int i = 0; i < 4; ++i) {
        const int row = r0 + quad * 4 + i;
        sup1[(long)row * OUT_F + wv * 16 + l16] = __float2half(acc[i]);
    }
}

// ---------------- SpMM layer 1: half-wave per edge ----------
__global__ __launch_bounds__(256) void spmm_l1_kernel(const int* __restrict__ rs,
                                                      const int2* __restrict__ bcv,
                                                      const __half* __restrict__ sup,
                                                      const float* __restrict__ bias,
                                                      float* __restrict__ out, int n) {
    const int wave = threadIdx.x >> 6;
    const int lane = threadIdx.x & 63;
    const int r = blockIdx.x * 4 + wave;
    if (r >= n) return;
    const int b  = r >> 7;
    const int rl = r & (RPB - 1);
    const int* rsb = rs + b * (RPB + 1);
    const int start = rsb[rl];
    const int end   = rsb[rl + 1];
    const int2* eb = bcv + (long)b * BCAP;
    const int eh = lane >> 5;
    const int li = lane & 31;
    const int f0 = li * 2;
    float acc0 = eh ? 0.f : bias[f0];
    float acc1 = eh ? 0.f : bias[f0 + 1];

    for (int base = start; base < end; base += 64) {
        const int m = min(64, end - base);
        int2 cvl = make_int2(0, 0);
        if (lane < m) cvl = eb[base + lane];
        for (int j = 0; j < m; j += 16) {
            int   p[8];
            float v[8];
#pragma unroll
            for (int q = 0; q < 8; ++q) {
                const int src = j + 2 * q + eh;
                p[q] = __shfl(cvl.x, src, 64);
                v[q] = __int_as_float(__shfl(cvl.y, src, 64));
            }
            __half2 s[8];
#pragma unroll
            for (int q = 0; q < 8; ++q)
                s[q] = *(const __half2*)(sup + (long)(p[q] & 0xFFFF) * OUT_F + f0);
#pragma unroll
            for (int q = 0; q < 8; ++q) {
                float2 gq = __half22float2(s[q]);
                acc0 += v[q] * gq.x; acc1 += v[q] * gq.y;
            }
        }
    }
    acc0 += __shfl_xor(acc0, 32, 64);
    acc1 += __shfl_xor(acc1, 32, 64);
    if (eh == 0)
        *(float2*)(out + (long)r * OUT_F + f0) = make_float2(acc0, acc1);
}

extern "C" void kernel_launch(void* const* d_in, const int* in_sizes, int n_in,
                              void* d_out, int out_size, void* d_ws, size_t ws_size,
                              hipStream_t stream) {
    const float* x    = (const float*)d_in[0];
    const int*   row0 = (const int*)d_in[1];
    const int*   col0 = (const int*)d_in[2];
    const float* val0 = (const float*)d_in[3];
    const int*   row1 = (const int*)d_in[4];
    const int*   col1 = (const int*)d_in[5];
    const float* val1 = (const float*)d_in[6];
    const float* W0   = (const float*)d_in[7];
    const float* b0   = (const float*)d_in[8];
    const float* W1   = (const float*)d_in[9];
    const float* b1   = (const float*)d_in[10];
    float* out = (float*)d_out;

    const int M = N_NODES;

    // Workspace: sup0 (N*128 fp16), sup1 (N*64 fp16, old h slot), bcv0/1,
    // rs0/1, gfill, wt0, wt1.
    __half* sup0 = (__half*)d_ws;
    __half* sup1 = sup0 + (long)N_NODES * HID_F;
    int2* bcv0   = (int2*)(sup1 + (long)N_NODES * HID_F);
    int2* bcv1   = bcv0 + (long)NBUCK * BCAP;
    int*  rs0    = (int*)(bcv1 + (long)NBUCK * BCAP);
    int*  rs1    = rs0 + NBUCK * (RPB + 1);
    int*  gfill  = rs1 + NBUCK * (RPB + 1);
    __half* wt0  = (__half*)(gfill + 2 * NBUCK + 2);  // [HID_F][IN_F]
    __half* wt1  = wt0 + IN_F * HID_F;                 // [OUT_F][HID_F]

    const int SPMM_B = (N_NODES + 3) / 4;

    // ---- Prep + bin + (sort || gemm0) ----
    prep_kernel<<<(IN_F * HID_F + 255) / 256, 256, 0, stream>>>(W0, W1, wt0, wt1, gfill);
    bin_kernel<<<dim3(BIN_NB, 2), BIN_T, 0, stream>>>(row0, col0, val0, row1, col1, val1,
                                                      gfill, bcv0, bcv1);
    mid_kernel<<<dim3(NBUCK, 3), MID_T, 0, stream>>>(gfill, bcv0, bcv1, rs0, rs1,
                                                     x, wt0, sup0, M);

    // ---- Fused: layer-0 aggregate + bias/relu + layer-1 GEMM ----
    agg_gemm_kernel<<<N_NODES / 16, 256, 0, stream>>>(rs0, bcv0, sup0, b0, wt1, sup1);

    // ---- Layer-1 aggregate ----
    spmm_l1_kernel<<<SPMM_B, 256, 0, stream>>>(rs1, bcv1, sup1, b1, out, N_NODES);
}